// Round 1
// baseline (357.703 us; speedup 1.0000x reference)
//
#include <hip/hip_runtime.h>
#include <stdint.h>

#define NCOMP 5
#define DM 1024
#define LN_EPS 1e-5f

typedef __attribute__((ext_vector_type(8))) __bf16 bf16x8;
typedef __attribute__((ext_vector_type(4))) float f32x4;

__device__ __forceinline__ unsigned short f2bf(float f) {
    unsigned u = __builtin_bit_cast(unsigned, f);
    u += 0x7fffu + ((u >> 16) & 1u);   // round-to-nearest-even
    return (unsigned short)(u >> 16);
}
__device__ __forceinline__ float bf2f(unsigned short h) {
    return __builtin_bit_cast(float, ((unsigned)h) << 16);
}

// -------- kernel 1: fused compartment LayerNorm, fp32 -> bf16 --------
__global__ __launch_bounds__(256) void ln_kernel(
    const float* __restrict__ x, const int* __restrict__ cid,
    const float* __restrict__ gamma, const float* __restrict__ beta,
    const float* __restrict__ scale, unsigned short* __restrict__ y)
{
    const int t = blockIdx.x;          // token
    const int tid = threadIdx.x;       // 256 threads, 4 elems each
    const float4 v = ((const float4*)(x + (size_t)t * DM))[tid];
    float s  = v.x + v.y + v.z + v.w;
    float ss = v.x * v.x + v.y * v.y + v.z * v.z + v.w * v.w;
#pragma unroll
    for (int off = 32; off > 0; off >>= 1) {
        s  += __shfl_down(s, off);
        ss += __shfl_down(ss, off);
    }
    __shared__ float red[8];
    const int wv = tid >> 6;
    if ((tid & 63) == 0) { red[wv] = s; red[4 + wv] = ss; }
    __syncthreads();
    const float sum = red[0] + red[1] + red[2] + red[3];
    const float sqs = red[4] + red[5] + red[6] + red[7];
    const float mu  = sum * (1.0f / DM);
    const float var = sqs * (1.0f / DM) - mu * mu;
    const float rs  = rsqrtf(var + LN_EPS);
    const int craw  = cid[t];
    const bool valid = craw < NCOMP;           // reference: valid = id < NC (negatives "valid")
    const int c = min(max(craw, 0), NCOMP - 1);
    const float sc = scale[c];
    const float4 g  = ((const float4*)(gamma + c * DM))[tid];
    const float4 bt = ((const float4*)(beta  + c * DM))[tid];
    float4 o;
    o.x = valid ? ((v.x - mu) * rs * g.x + bt.x) * sc : v.x;
    o.y = valid ? ((v.y - mu) * rs * g.y + bt.y) * sc : v.y;
    o.z = valid ? ((v.z - mu) * rs * g.z + bt.z) * sc : v.z;
    o.w = valid ? ((v.w - mu) * rs * g.w + bt.w) * sc : v.w;
    uint2 p;
    p.x = (unsigned)f2bf(o.x) | ((unsigned)f2bf(o.y) << 16);
    p.y = (unsigned)f2bf(o.z) | ((unsigned)f2bf(o.w) << 16);
    *(uint2*)(y + (size_t)t * DM + tid * 4) = p;
}

// -------- kernel 2: W fp32 -> bf16 --------
__global__ __launch_bounds__(256) void cvt_kernel(
    const float* __restrict__ W, unsigned short* __restrict__ Wb)
{
    const int i = (blockIdx.x * 256 + threadIdx.x) * 4;
    const float4 v = *(const float4*)(W + i);
    uint2 p;
    p.x = (unsigned)f2bf(v.x) | ((unsigned)f2bf(v.y) << 16);
    p.y = (unsigned)f2bf(v.z) | ((unsigned)f2bf(v.w) << 16);
    *(uint2*)(Wb + i) = p;
}

// -------- kernel 3: C = A * Bt^T + A + bias (m97 structure) --------
// A = y bf16 [M,1024] row-major (K-contiguous); Bt = W bf16 [1024,1024] (N rows, K-contiguous)
__device__ __forceinline__ void gld_lds16(const unsigned short* g, unsigned short* l) {
    __builtin_amdgcn_global_load_lds(
        (const __attribute__((address_space(1))) unsigned int*)(uintptr_t)g,
        (__attribute__((address_space(3))) unsigned int*)(uintptr_t)l,
        16, 0, 0);
}

__global__ __launch_bounds__(256) void gemm_kernel(
    const unsigned short* __restrict__ A,
    const unsigned short* __restrict__ Bt,
    const float* __restrict__ bias,
    float* __restrict__ C, int M)
{
    constexpr int K = 1024, N = 1024, BK = 32, TM = 128, TN = 128;
    __shared__ __align__(16) unsigned short As[TM * BK];   // 8 KB
    __shared__ __align__(16) unsigned short Bs[TN * BK];   // 8 KB

    const int tid  = threadIdx.x;
    const int bm   = blockIdx.x * TM;
    const int bn   = blockIdx.y * TN;
    const int lane = tid & 63;
    const int wave = tid >> 6;
    const int wm   = (wave >> 1) * 64;   // wave m-offset in tile
    const int wn   = (wave & 1) * 64;    // wave n-offset in tile

    // staging: chunk c = tid (issue 0) and tid+256 (issue 1); chunk -> row c/4, col (c%4)*8
    const int r0 = tid >> 2;
    const int c0 = (tid & 3) * 8;
    const unsigned short* Ag  = A  + (size_t)(bm + r0) * K + c0;
    const unsigned short* Ag2 = A  + (size_t)(bm + 64 + r0) * K + c0;
    const unsigned short* Bg  = Bt + (size_t)(bn + r0) * K + c0;
    const unsigned short* Bg2 = Bt + (size_t)(bn + 64 + r0) * K + c0;
    unsigned short* Asl  = &As[(size_t)tid * 8];
    unsigned short* Asl2 = &As[(size_t)(tid + 256) * 8];
    unsigned short* Bsl  = &Bs[(size_t)tid * 8];
    unsigned short* Bsl2 = &Bs[(size_t)(tid + 256) * 8];

    f32x4 acc[4][4] = {};

    const int qk = (lane >> 4) * 8;    // k-offset of this lane's fragment
    const int fr = lane & 15;          // m (A) / n (B) index within 16-tile

    for (int k0 = 0; k0 < K; k0 += BK) {
        __syncthreads();               // prev iter's LDS reads done
        gld_lds16(Ag  + k0, Asl);
        gld_lds16(Ag2 + k0, Asl2);
        gld_lds16(Bg  + k0, Bsl);
        gld_lds16(Bg2 + k0, Bsl2);
        __syncthreads();               // staging complete (vmcnt drained by barrier)

        bf16x8 af[4], bfr[4];
#pragma unroll
        for (int i = 0; i < 4; i++)
            af[i] = *(const bf16x8*)&As[(wm + i * 16 + fr) * BK + qk];
#pragma unroll
        for (int i = 0; i < 4; i++)
            bfr[i] = *(const bf16x8*)&Bs[(wn + i * 16 + fr) * BK + qk];
#pragma unroll
        for (int mi = 0; mi < 4; mi++)
#pragma unroll
            for (int ni = 0; ni < 4; ni++)
                acc[mi][ni] = __builtin_amdgcn_mfma_f32_16x16x32_bf16(
                    af[mi], bfr[ni], acc[mi][ni], 0, 0, 0);
    }

    // epilogue: out = acc + y + bias   (C/D layout: col=lane&15, row=(lane>>4)*4+reg)
#pragma unroll
    for (int ni = 0; ni < 4; ni++) {
        const int col = bn + wn + ni * 16 + fr;
        const float bv = bias[col];
#pragma unroll
        for (int mi = 0; mi < 4; mi++) {
#pragma unroll
            for (int r = 0; r < 4; r++) {
                const int row = bm + wm + mi * 16 + (lane >> 4) * 4 + r;
                const float yv = bf2f(A[(size_t)row * K + col]);   // K==N==1024
                C[(size_t)row * N + col] = acc[mi][ni][r] + yv + bv;
            }
        }
    }
}

extern "C" void kernel_launch(void* const* d_in, const int* in_sizes, int n_in,
                              void* d_out, int out_size, void* d_ws, size_t ws_size,
                              hipStream_t stream)
{
    const float* x     = (const float*)d_in[0];
    const int*   cid   = (const int*)d_in[1];
    const float* gamma = (const float*)d_in[2];
    const float* beta  = (const float*)d_in[3];
    const float* scale = (const float*)d_in[4];
    const float* W     = (const float*)d_in[5];
    const float* bias  = (const float*)d_in[6];
    float* out = (float*)d_out;

    const int M = in_sizes[0] / DM;           // 32768 tokens
    unsigned short* yb = (unsigned short*)d_ws;            // M*1024 bf16 = 64 MB
    unsigned short* Wb = yb + (size_t)M * DM;              // 1024*1024 bf16 = 2 MB

    ln_kernel<<<M, 256, 0, stream>>>(x, cid, gamma, beta, scale, yb);
    cvt_kernel<<<(DM * DM) / 1024, 256, 0, stream>>>(W, Wb);
    dim3 grid(M / 128, DM / 128);
    gemm_kernel<<<grid, 256, 0, stream>>>(yb, Wb, bias, out, M);
}